// Round 7
// baseline (156.137 us; speedup 1.0000x reference)
//
#include <hip/hip_runtime.h>
#include <hip/hip_bf16.h>

#define CC 256
#define NN 4096
#define CQ 32
#define LOG2E 1.4426950408889634f

using short8 = __attribute__((ext_vector_type(8))) short;
using f32x4  = __attribute__((ext_vector_type(4))) float;

static __device__ __forceinline__ short f2bf(float f) {
  __hip_bfloat16 h = __float2bfloat16(f);
  return *reinterpret_cast<short*>(&h);
}

// ---------------------------------------------------------------------------
// Kernel 1: QKV via MFMA, x-stationary.  512 threads (8 waves), grid 64x4.
// W fp32->bf16 conversion fused in-register (W is 320 KB, L2-resident; no
// prep kernel).  Stage x[256c x 64n] -> LDS bf16 [n][c]; wave w computes
// r-tiles {2w, 2w+1} (+ tile 16+w for w<4).  v repacked via per-wave LDS ->
// coalesced 16B stores.
// ---------------------------------------------------------------------------
__global__ __launch_bounds__(512, 2) void qkv_kernel(
    const float* __restrict__ x,
    const float* __restrict__ Wq, const float* __restrict__ bq,
    const float* __restrict__ Wk, const float* __restrict__ bk,
    const float* __restrict__ Wv, const float* __restrict__ bv,
    __hip_bfloat16* __restrict__ qb, __hip_bfloat16* __restrict__ kb,
    __hip_bfloat16* __restrict__ vb)
{
  const int b  = blockIdx.y;
  const int n0 = blockIdx.x * 64;
  const int tid = threadIdx.x;
  const int lane = tid & 63;
  const int w = __builtin_amdgcn_readfirstlane(tid >> 6);  // wave 0..7
  const int l15 = lane & 15, quad = lane >> 4;

  __shared__ __align__(16) short Xs[64][264];     // [n][c] bf16, 33792 B
  __shared__ __align__(16) short Vr[8][16][72];   // per-wave repack, 18432 B

  // ---- stage x tile: thread covers n = tid&63, 8-c runs ----
  const int sn = tid & 63, cg8 = tid >> 6;
  const float* xcol = x + (size_t)b*CC*NN + n0 + sn;
#pragma unroll
  for (int it = 0; it < 4; it++) {
    int cbase = it*64 + cg8*8;
    float v[8];
#pragma unroll
    for (int j = 0; j < 8; j++) v[j] = xcol[(size_t)(cbase + j)*NN];
    short8 sv;
#pragma unroll
    for (int j = 0; j < 8; j++) sv[j] = f2bf(v[j]);
    *reinterpret_cast<short8*>(&Xs[sn][cbase]) = sv;
  }
  __syncthreads();

#define QKV_TILE(T) { \
    const int t_ = (T); \
    const float* wr; \
    { int R = t_*16 + l15; \
      if (t_ < 2)      wr = Wq + (size_t)R*CC; \
      else if (t_ < 4) wr = Wk + (size_t)(R-32)*CC; \
      else             wr = Wv + (size_t)(R-64)*CC; } \
    short8 Af[8]; \
    _Pragma("unroll") \
    for (int kc = 0; kc < 8; kc++) { \
      float4 fa = *(const float4*)(wr + kc*32 + quad*8); \
      float4 fc = *(const float4*)(wr + kc*32 + quad*8 + 4); \
      short8 o; \
      o[0]=f2bf(fa.x); o[1]=f2bf(fa.y); o[2]=f2bf(fa.z); o[3]=f2bf(fa.w); \
      o[4]=f2bf(fc.x); o[5]=f2bf(fc.y); o[6]=f2bf(fc.z); o[7]=f2bf(fc.w); \
      Af[kc] = o; \
    } \
    f32x4 ac0 = {0.f,0.f,0.f,0.f}, ac1 = {0.f,0.f,0.f,0.f}; \
    f32x4 ac2 = {0.f,0.f,0.f,0.f}, ac3 = {0.f,0.f,0.f,0.f}; \
    _Pragma("unroll") \
    for (int kc = 0; kc < 8; kc++) { \
      short8 B0 = *(const short8*)(&Xs[     l15][kc*32 + quad*8]); \
      short8 B1 = *(const short8*)(&Xs[16 + l15][kc*32 + quad*8]); \
      short8 B2 = *(const short8*)(&Xs[32 + l15][kc*32 + quad*8]); \
      short8 B3 = *(const short8*)(&Xs[48 + l15][kc*32 + quad*8]); \
      ac0 = __builtin_amdgcn_mfma_f32_16x16x32_bf16(Af[kc], B0, ac0, 0,0,0); \
      ac1 = __builtin_amdgcn_mfma_f32_16x16x32_bf16(Af[kc], B1, ac1, 0,0,0); \
      ac2 = __builtin_amdgcn_mfma_f32_16x16x32_bf16(Af[kc], B2, ac2, 0,0,0); \
      ac3 = __builtin_amdgcn_mfma_f32_16x16x32_bf16(Af[kc], B3, ac3, 0,0,0); \
    } \
    if (t_ < 2) { \
      int d0 = t_*16; \
      _Pragma("unroll") \
      for (int r = 0; r < 4; r++) { \
        int d = d0 + quad*4 + r; float bb = bq[d]; \
        qb[(size_t)b*NN*CQ + (size_t)(n0      + l15)*CQ + d] = __float2bfloat16(LOG2E*(ac0[r] + bb)); \
        qb[(size_t)b*NN*CQ + (size_t)(n0 + 16 + l15)*CQ + d] = __float2bfloat16(LOG2E*(ac1[r] + bb)); \
        qb[(size_t)b*NN*CQ + (size_t)(n0 + 32 + l15)*CQ + d] = __float2bfloat16(LOG2E*(ac2[r] + bb)); \
        qb[(size_t)b*NN*CQ + (size_t)(n0 + 48 + l15)*CQ + d] = __float2bfloat16(LOG2E*(ac3[r] + bb)); \
      } \
    } else if (t_ < 4) { \
      int d0 = (t_-2)*16; \
      _Pragma("unroll") \
      for (int r = 0; r < 4; r++) { \
        int d = d0 + quad*4 + r; float bb = bk[d]; \
        kb[(size_t)b*NN*CQ + (size_t)(n0      + l15)*CQ + d] = __float2bfloat16(ac0[r] + bb); \
        kb[(size_t)b*NN*CQ + (size_t)(n0 + 16 + l15)*CQ + d] = __float2bfloat16(ac1[r] + bb); \
        kb[(size_t)b*NN*CQ + (size_t)(n0 + 32 + l15)*CQ + d] = __float2bfloat16(ac2[r] + bb); \
        kb[(size_t)b*NN*CQ + (size_t)(n0 + 48 + l15)*CQ + d] = __float2bfloat16(ac3[r] + bb); \
      } \
    } else { \
      int rv0 = (t_-4)*16; \
      _Pragma("unroll") \
      for (int r = 0; r < 4; r++) { \
        float bb = bv[rv0 + quad*4 + r]; \
        Vr[w][quad*4 + r][     l15] = f2bf(ac0[r] + bb); \
        Vr[w][quad*4 + r][16 + l15] = f2bf(ac1[r] + bb); \
        Vr[w][quad*4 + r][32 + l15] = f2bf(ac2[r] + bb); \
        Vr[w][quad*4 + r][48 + l15] = f2bf(ac3[r] + bb); \
      } \
      int row = lane >> 2, cb = (lane & 3)*16; \
      short8 t0 = *(const short8*)(&Vr[w][row][cb]); \
      short8 t1 = *(const short8*)(&Vr[w][row][cb + 8]); \
      *(short8*)(vb + ((size_t)b*CC + rv0 + row)*NN + n0 + cb)     = t0; \
      *(short8*)(vb + ((size_t)b*CC + rv0 + row)*NN + n0 + cb + 8) = t1; \
    } }

  QKV_TILE(2*w);
  QKV_TILE(2*w + 1);
  if (w < 4) { QKV_TILE(16 + w); }
#undef QKV_TILE
}

// ---------------------------------------------------------------------------
// Kernel 2: O = softmax(QK^T) V, epilogue gamma*O + x.  512 threads, 8 waves.
// Wave (sg, mh): S rows sg*16 x m-half mh; PV: c-strip sg*64 x all 64 n over
// K=32 (its m-half).  KEY: V staging is WAVE-PRIVATE (Vsp[w]) -- PV wave
// (sg,mh) reads exactly the patch it stages, per-wave LDS ops are in-order,
// so V needs NO barrier.  Only P crosses waves: Ps double-buffered => ONE
// __syncthreads per tile (vs 2 in round 6; barriers phase-lock co-resident
// waves and were the latency exposure).  mh halves combined via LDS at end.
// All acc[] subscripts compile-time const (spill trap).
// ---------------------------------------------------------------------------
__global__ __launch_bounds__(512, 2) void attn_kernel(
    const __hip_bfloat16* __restrict__ qb, const __hip_bfloat16* __restrict__ kb,
    const __hip_bfloat16* __restrict__ vb,
    const float* __restrict__ x, const float* __restrict__ gamma,
    float* __restrict__ out)
{
  const int Bk = blockIdx.x;
  const int b = (Bk & 7) >> 1;                       // 2 XCDs per batch
  const int n0 = ((Bk >> 3)*2 + (Bk & 1)) * 64;      // n-tile 0..63
  const int tid = threadIdx.x;
  const int lane = tid & 63;
  const int w = __builtin_amdgcn_readfirstlane(tid >> 6);   // 0..7
  const int sg = w & 3;                               // S row-group / c-strip
  const int mh = w >> 2;                              // m-half 0/1
  const int l15 = lane & 15, quad = lane >> 4;

  __shared__ __align__(16) short Vsp[8][64][40];     // wave-private V, 40960 B
  __shared__ __align__(16) short Ps[2][2][64][40];   // [buf][mh][n][m], 20480 B
  __shared__ float Lbuf2[2][64];

  const short* qbase = (const short*)qb + (size_t)b*NN*CQ;
  const short* kbase = (const short*)kb + (size_t)b*NN*CQ;
  const short* vbase = (const short*)vb + (size_t)b*CC*NN;

  short8 aq = *(const short8*)(qbase + (size_t)(n0 + sg*16 + l15)*CQ + quad*8);

  // wave-private V staging: lane covers rows vrow+{0,16,32,48}, chunk vch
  const int vrow = lane >> 2, vch = lane & 3;
  const short* vwave = vbase + (size_t)(sg*64)*NN + mh*32 + vch*8;

  short8 nv0, nv1, nv2, nv3, kf0, kf1, nk0, nk1;
  {
    const short* vp = vwave + (size_t)vrow*NN;
    nv0 = *(const short8*)(vp);
    nv1 = *(const short8*)(vp + (size_t)16*NN);
    nv2 = *(const short8*)(vp + (size_t)32*NN);
    nv3 = *(const short8*)(vp + (size_t)48*NN);
  }
  kf0 = *(const short8*)(kbase + (size_t)(mh*32 +      l15)*CQ + quad*8);
  kf1 = *(const short8*)(kbase + (size_t)(mh*32 + 16 + l15)*CQ + quad*8);
  *(short8*)(&Vsp[w][vrow     ][vch*8]) = nv0;
  *(short8*)(&Vsp[w][vrow + 16][vch*8]) = nv1;
  *(short8*)(&Vsp[w][vrow + 32][vch*8]) = nv2;
  *(short8*)(&Vsp[w][vrow + 48][vch*8]) = nv3;

  f32x4 acc[4][4];
#pragma unroll
  for (int cg = 0; cg < 4; cg++)
#pragma unroll
    for (int ng = 0; ng < 4; ng++) acc[cg][ng] = (f32x4){0.f,0.f,0.f,0.f};
  float lsum[4] = {0.f,0.f,0.f,0.f};

  for (int T = 0; T < 64; T++) {
    // prefetch tile T+1 (global -> regs); consumed after this tile's PV reads
    if (T < 63) {
      const short* vp = vwave + (size_t)vrow*NN + (T+1)*64;
      nv0 = *(const short8*)(vp);
      nv1 = *(const short8*)(vp + (size_t)16*NN);
      nv2 = *(const short8*)(vp + (size_t)32*NN);
      nv3 = *(const short8*)(vp + (size_t)48*NN);
      nk0 = *(const short8*)(kbase + (size_t)((T+1)*64 + mh*32 +      l15)*CQ + quad*8);
      nk1 = *(const short8*)(kbase + (size_t)((T+1)*64 + mh*32 + 16 + l15)*CQ + quad*8);
    }

    // S' for rows sg*16.., m-half mh of tile T
    f32x4 z = {0.f,0.f,0.f,0.f};
    f32x4 S0 = __builtin_amdgcn_mfma_f32_16x16x32_bf16(aq, kf0, z, 0,0,0);
    f32x4 S1 = __builtin_amdgcn_mfma_f32_16x16x32_bf16(aq, kf1, z, 0,0,0);
    const int pb = T & 1;
#pragma unroll
    for (int r = 0; r < 4; r++) {
      float e0 = __builtin_amdgcn_exp2f(S0[r]);
      float e1 = __builtin_amdgcn_exp2f(S1[r]);
      lsum[r] += e0 + e1;
      Ps[pb][mh][sg*16 + quad*4 + r][     l15] = f2bf(e0);
      Ps[pb][mh][sg*16 + quad*4 + r][16 + l15] = f2bf(e1);
    }
    __syncthreads();   // the ONLY barrier: publishes Ps(T) across waves

    short8 ap0 = *(const short8*)(&Ps[pb][mh][     l15][quad*8]);
    short8 ap1 = *(const short8*)(&Ps[pb][mh][16 + l15][quad*8]);
    short8 ap2 = *(const short8*)(&Ps[pb][mh][32 + l15][quad*8]);
    short8 ap3 = *(const short8*)(&Ps[pb][mh][48 + l15][quad*8]);
#pragma unroll
    for (int cg = 0; cg < 4; cg++) {
      short8 av = *(const short8*)(&Vsp[w][cg*16 + l15][quad*8]);
      acc[cg][0] = __builtin_amdgcn_mfma_f32_16x16x32_bf16(av, ap0, acc[cg][0], 0,0,0);
      acc[cg][1] = __builtin_amdgcn_mfma_f32_16x16x32_bf16(av, ap1, acc[cg][1], 0,0,0);
      acc[cg][2] = __builtin_amdgcn_mfma_f32_16x16x32_bf16(av, ap2, acc[cg][2], 0,0,0);
      acc[cg][3] = __builtin_amdgcn_mfma_f32_16x16x32_bf16(av, ap3, acc[cg][3], 0,0,0);
    }

    // wave-private V update: in-order per-wave LDS => safe without barrier
    if (T < 63) {
      *(short8*)(&Vsp[w][vrow     ][vch*8]) = nv0;
      *(short8*)(&Vsp[w][vrow + 16][vch*8]) = nv1;
      *(short8*)(&Vsp[w][vrow + 32][vch*8]) = nv2;
      *(short8*)(&Vsp[w][vrow + 48][vch*8]) = nv3;
      kf0 = nk0; kf1 = nk1;
    }
  }

  // ---- L: reduce over l15, publish per m-half ----
#pragma unroll
  for (int r = 0; r < 4; r++) {
    float s = lsum[r];
    s += __shfl_xor(s, 1); s += __shfl_xor(s, 2);
    s += __shfl_xor(s, 4); s += __shfl_xor(s, 8);
    if (l15 == 0) Lbuf2[mh][sg*16 + quad*4 + r] = s;
  }

  // ---- combine mh halves of acc via LDS (2 rounds of 2 c-strips) ----
  float* poolf = reinterpret_cast<float*>(&Vsp[0][0][0]);   // 32 KB of 40 KB
  __syncthreads();
#pragma unroll
  for (int g = 0; g < 2; g++) {
    if (mh == 1 && (sg >> 1) == g) {
#pragma unroll
      for (int cg = 0; cg < 4; cg++)
#pragma unroll
        for (int ng = 0; ng < 4; ng++)
#pragma unroll
          for (int r = 0; r < 4; r++)
            poolf[(sg & 1)*4096 + (cg*16 + quad*4 + r)*64 + ng*16 + l15] = acc[cg][ng][r];
    }
    __syncthreads();
    if (mh == 0 && (sg >> 1) == g) {
#pragma unroll
      for (int cg = 0; cg < 4; cg++)
#pragma unroll
        for (int ng = 0; ng < 4; ng++)
#pragma unroll
          for (int r = 0; r < 4; r++)
            acc[cg][ng][r] += poolf[(sg & 1)*4096 + (cg*16 + quad*4 + r)*64 + ng*16 + l15];
    }
    __syncthreads();
  }

  // ---- epilogue (mh==0 waves): out = gamma*O/l + x, coalesced rows ----
  if (mh == 0) {
    const float gm = gamma[0];
    float Lv[4];
#pragma unroll
    for (int ng = 0; ng < 4; ng++)
      Lv[ng] = 1.0f / (Lbuf2[0][ng*16 + l15] + Lbuf2[1][ng*16 + l15]);
#pragma unroll
    for (int cg = 0; cg < 4; cg++) {
#pragma unroll
      for (int ng = 0; ng < 4; ng++) {
#pragma unroll
        for (int r = 0; r < 4; r++) {
          size_t idx = ((size_t)b*CC + sg*64 + cg*16 + quad*4 + r)*NN + n0 + ng*16 + l15;
          out[idx] = gm * acc[cg][ng][r] * Lv[ng] + x[idx];
        }
      }
    }
  }
}

// ---------------------------------------------------------------------------
extern "C" void kernel_launch(void* const* d_in, const int* in_sizes, int n_in,
                              void* d_out, int out_size, void* d_ws, size_t ws_size,
                              hipStream_t stream) {
  const float* x     = (const float*)d_in[0];
  const float* Wq    = (const float*)d_in[1];
  const float* bq    = (const float*)d_in[2];
  const float* Wk    = (const float*)d_in[3];
  const float* bk    = (const float*)d_in[4];
  const float* Wv    = (const float*)d_in[5];
  const float* bv    = (const float*)d_in[6];
  const float* gamma = (const float*)d_in[7];
  float* out = (float*)d_out;

  char* ws = (char*)d_ws;
  if (ws_size < (10u << 20)) return;
  __hip_bfloat16* qb = (__hip_bfloat16*)(ws);                 // [B][N][32]  1 MB
  __hip_bfloat16* kb = (__hip_bfloat16*)(ws + (1u << 20));    // [B][N][32]  1 MB
  __hip_bfloat16* vb = (__hip_bfloat16*)(ws + (2u << 20));    // [B][C][N]   8 MB

  qkv_kernel<<<dim3(64, 4), 512, 0, stream>>>(x, Wq, bq, Wk, bk, Wv, bv, qb, kb, vb);
  attn_kernel<<<dim3(256), 512, 0, stream>>>(qb, kb, vb, x, gamma, out);
}